// Round 14
// baseline (292.312 us; speedup 1.0000x reference)
//
#include <hip/hip_runtime.h>
#include <math.h>

#define B_    4
#define HW_   4800
#define K_    8
#define IMGD  192
#define PTD   128
#define NH_   6
#define DH_   64
#define INNER 384
#define KVIN  154
#define QT    16
#define NJ    128    // QT * K_
#define XBS   168    // fp16 X row stride (336B)
#define AST   392    // alias stride: f16 rows [16][AST], fp32 q rows [16][AST floats]
#define KTQ   6      // Q-proj k-steps (192)
#define KTK   5      // K/V k-steps (154 -> 160, zero-padded both sides)
#define KTO   12     // out-proj k-steps (384)

#define GC    64     // kNN bucket grid cells per dim
#define NCELL (GC * GC)
#define CS    (1.0f / 64.0f)

typedef _Float16 f16;
typedef __attribute__((ext_vector_type(8))) _Float16 f16x8;
typedef __attribute__((ext_vector_type(4))) float f32x4;

// ---------------------------------------------------------------------------
// Kernel 0: pack all weights into fp16 MFMA fragment order.
// frag element (l,j): k = kt*32+(l>>4)*8+j, n = nt*16+(l&15)
// [pwq f=0..143 | pwk 144..263 | pwv 264..383 | pwo 384..671], 512 elems/frag
// ---------------------------------------------------------------------------
__global__ __launch_bounds__(256) void pack_kernel(
    const float* __restrict__ Wq, const float* __restrict__ Wkv,
    const float* __restrict__ Wout, f16* __restrict__ pw)
{
  const int e = blockIdx.x * 256 + threadIdx.x;     // 672*512 = 344064 total
  if (e >= 672 * 512) return;
  const int f = e >> 9, r = e & 511, l = r >> 3, j = r & 7;
  const int lm = l & 15, kin = (l >> 4) * 8 + j;
  float v;
  if (f < 144) {                                    // Wq [192][384]
    const int nt = f / 6, kt = f % 6;
    v = Wq[(size_t)(kt * 32 + kin) * INNER + nt * 16 + lm];
  } else if (f < 264) {                             // Wk = Wkv[:, :384]
    const int g = f - 144, nt = g / 5, kt = g % 5, k = kt * 32 + kin;
    v = (k < KVIN) ? Wkv[(size_t)k * (2 * INNER) + nt * 16 + lm] : 0.f;
  } else if (f < 384) {                             // Wv = Wkv[:, 384:]
    const int g = f - 264, nt = g / 5, kt = g % 5, k = kt * 32 + kin;
    v = (k < KVIN) ? Wkv[(size_t)k * (2 * INNER) + INNER + nt * 16 + lm] : 0.f;
  } else {                                          // Wout [384][384]
    const int g = f - 384, nt = g / 12, kt = g % 12;
    v = Wout[(size_t)(kt * 32 + kin) * INNER + nt * 16 + lm];
  }
  pw[e] = (f16)v;
}

// ---------------------------------------------------------------------------
// Kernel B: per-batch counting sort of proj_uv into a 64x64 cell grid.
// ---------------------------------------------------------------------------
__global__ __launch_bounds__(1024) void build_kernel(
    const float* __restrict__ proj_uv,
    float2* __restrict__ spts,
    unsigned short* __restrict__ sidx,
    unsigned short* __restrict__ cstart)
{
  __shared__ unsigned cnt[NCELL];
  __shared__ unsigned start[NCELL];
  __shared__ unsigned wsum[16];

  const int b   = blockIdx.x;
  const int tid = threadIdx.x;
  const int lane = tid & 63, wid = tid >> 6;
  const float2* pv = reinterpret_cast<const float2*>(proj_uv + (size_t)b * HW_ * 2);

  for (int c = tid; c < NCELL; c += 1024) cnt[c] = 0u;
  __syncthreads();

  for (int i = tid; i < HW_; i += 1024) {
    const float2 p = pv[i];
    const int cx = min(GC - 1, max(0, (int)(p.x * GC)));
    const int cy = min(GC - 1, max(0, (int)(p.y * GC)));
    atomicAdd(&cnt[cy * GC + cx], 1u);
  }
  __syncthreads();

  const int c0 = tid * 4;
  const unsigned v0 = cnt[c0], v1 = cnt[c0 + 1], v2 = cnt[c0 + 2], v3 = cnt[c0 + 3];
  const unsigned mysum = v0 + v1 + v2 + v3;
  unsigned inc = mysum;
#pragma unroll
  for (int off = 1; off < 64; off <<= 1) {
    const unsigned u = (unsigned)__shfl_up((int)inc, off);
    if (lane >= off) inc += u;
  }
  if (lane == 63) wsum[wid] = inc;
  __syncthreads();
  if (tid == 0) {
    unsigned s = 0;
#pragma unroll
    for (int wv = 0; wv < 16; ++wv) { const unsigned t = wsum[wv]; wsum[wv] = s; s += t; }
  }
  __syncthreads();
  unsigned base = wsum[wid] + inc - mysum;
  start[c0] = base;
  start[c0 + 1] = base + v0;
  start[c0 + 2] = base + v0 + v1;
  start[c0 + 3] = base + v0 + v1 + v2;
  unsigned short* cs = cstart + (size_t)b * (NCELL + 1);
  cs[c0]     = (unsigned short)start[c0];
  cs[c0 + 1] = (unsigned short)start[c0 + 1];
  cs[c0 + 2] = (unsigned short)start[c0 + 2];
  cs[c0 + 3] = (unsigned short)start[c0 + 3];
  if (tid == 0) cs[NCELL] = (unsigned short)HW_;
  __syncthreads();

  for (int i = tid; i < HW_; i += 1024) {
    const float2 p = pv[i];
    const int cx = min(GC - 1, max(0, (int)(p.x * GC)));
    const int cy = min(GC - 1, max(0, (int)(p.y * GC)));
    const unsigned slot = atomicAdd(&start[cy * GC + cx], 1u);
    spts[(size_t)b * HW_ + slot] = p;
    sidx[(size_t)b * HW_ + slot] = (unsigned short)i;
  }
}

// ---------------------------------------------------------------------------
// Kernel 1: kNN via ring scan over the cell grid (r11-fixed, r12/13-passed).
// ---------------------------------------------------------------------------
#define SCAN_CELL(cyv, cxv)                                                   \
  {                                                                           \
    const int c = (cyv) * GC + (cxv);                                         \
    const int s0 = s_cs[c], s1 = s_cs[c + 1];                                 \
    for (int s = s0; s < s1; ++s) {                                           \
      const float2 p = s_p[s];                                                \
      const int n = (int)s_i[s];                                              \
      const float sqp = p.x * p.x + p.y * p.y;       /* f32 no fma */         \
      const float dot = fmaf(qy, p.y, qx * p.x);     /* BLAS K=2 fma */       \
      const float d   = (sqq + sqp) - 2.0f * dot;                             \
      const bool enter = (d < dist[K_ - 1]) ||                                \
                         (d == dist[K_ - 1] && n < ind[K_ - 1]);              \
      if (enter) {                                                            \
        bool placed = false;                                                  \
        _Pragma("unroll")                                                     \
        for (int t = K_ - 1; t >= 1; --t) {                                   \
          if (!placed) {                                                      \
            const bool lt = (d < dist[t - 1]) ||                              \
                            (d == dist[t - 1] && n < ind[t - 1]);             \
            if (lt) { dist[t] = dist[t - 1]; ind[t] = ind[t - 1]; }           \
            else    { dist[t] = d; ind[t] = n; placed = true; }               \
          }                                                                   \
        }                                                                     \
        if (!placed) { dist[0] = d; ind[0] = n; }                             \
      }                                                                       \
    }                                                                         \
  }

__global__ __launch_bounds__(256) void knn_kernel(
    const float* __restrict__ img_uv,
    const float2* __restrict__ spts,
    const unsigned short* __restrict__ sidx,
    const unsigned short* __restrict__ cstart,
    int* __restrict__ idx_out)
{
#pragma clang fp contract(off)
  __shared__ float2 s_p[HW_];
  __shared__ unsigned short s_i[HW_];
  __shared__ unsigned short s_cs[NCELL + 1];

  const int tid = threadIdx.x;
  const int b   = blockIdx.y;
  const int q   = blockIdx.x * 256 + tid;

  {
    const float2* gp = spts + (size_t)b * HW_;
    const unsigned short* gi = sidx + (size_t)b * HW_;
    const unsigned short* gc = cstart + (size_t)b * (NCELL + 1);
    for (int i = tid; i < HW_; i += 256) { s_p[i] = gp[i]; s_i[i] = gi[i]; }
    for (int i = tid; i < NCELL + 1; i += 256) s_cs[i] = gc[i];
  }
  __syncthreads();
  if (q >= HW_) return;

  const float qx = img_uv[q * 2 + 0];
  const float qy = img_uv[q * 2 + 1];
  const float sqq = qx * qx + qy * qy;

  const int cellx = min(GC - 1, max(0, (int)(qx * GC)));
  const int celly = min(GC - 1, max(0, (int)(qy * GC)));

  float dist[K_];
  int   ind[K_];
#pragma unroll
  for (int s = 0; s < K_; ++s) { dist[s] = 3.4e38f; ind[s] = 0x7fffffff; }

  for (int r = 0; r < GC; ++r) {
    if (r >= 2 && dist[K_ - 1] < 1e38f) {
      const float rb = (float)(r - 1) * CS;
      if (rb * rb > dist[K_ - 1] + 1e-4f) break;
    }
    const int ylo = max(0, celly - r), yhi = min(GC - 1, celly + r);
    for (int cy = ylo; cy <= yhi; ++cy) {
      const bool edge = (cy == celly - r) || (cy == celly + r);
      if (edge) {
        const int xlo = max(0, cellx - r), xhi = min(GC - 1, cellx + r);
        for (int cx = xlo; cx <= xhi; ++cx) SCAN_CELL(cy, cx);
      } else {
        if (cellx - r >= 0)      SCAN_CELL(cy, cellx - r);
        if (cellx + r <= GC - 1) SCAN_CELL(cy, cellx + r);
      }
    }
  }

  int* dst = idx_out + ((size_t)b * HW_ + q) * K_;
#pragma unroll
  for (int s = 0; s < K_; ++s) dst[s] = ind[s];
}

// ---------------------------------------------------------------------------
// Kernel 2: fused fp16-MFMA pipeline, QT=16 (r14). 16 query rows fill the
// MFMA M-dim exactly: Q-proj and out-proj A-tiles are all-real (zero-pad rows
// and their zero-fill phases deleted). V/xbar per-head 16-row tiles.
// 79.7KB LDS -> 2 blocks/CU; 300x4 grid halves block generations per CU.
// ---------------------------------------------------------------------------
__global__ __launch_bounds__(256, 2) void fused_kernel(
    const float* __restrict__ feat_2d,
    const float* __restrict__ feat_3d,
    const float* __restrict__ img_uv,
    const float* __restrict__ ln_gamma,
    const float* __restrict__ q_gamma,
    const float* __restrict__ k_gamma,
    const f16*   __restrict__ pw,
    const int*   __restrict__ idx_ws,
    float* __restrict__ out)
{
  __shared__ alignas(16) f16   s_X[NJ][XBS];       // 128 X rows; later xbar[96]
  __shared__ alignas(16) float s_regA[QT * AST];   // q fp32[16] | alias f16[16][AST]
  __shared__ alignas(16) float s_attn[QT][NH_][K_];
  __shared__ alignas(16) float s_kss[NJ][NH_];
  __shared__ alignas(16) float s_ksc[NJ][NH_];
  __shared__ float s_qss[QT][NH_];
  __shared__ float s_mask[NJ];
  __shared__ int   s_idx[NJ];
  __shared__ float s_offx[NJ];
  __shared__ float s_offy[NJ];

  f16* s_f16 = reinterpret_cast<f16*>(s_regA);     // rows [16][AST] (bytes 0..12543)

  const int tid = threadIdx.x;
  const int b   = blockIdx.y;
  // bijective XCD swizzle for 300 tiles (300 = 4*38 + 4*37)
  const int orig = blockIdx.x;
  const int xcd  = orig & 7, id8 = orig >> 3;
  const int bx   = (xcd < 4) ? xcd * 38 + id8 : 152 + (xcd - 4) * 37 + id8;
  const int q0  = bx * QT;
  const int l   = tid & 63;
  const int w   = tid >> 6;                        // 0..3
  const int lm  = l & 15;
  const int lg  = l >> 4;

  const f16* pwq = pw;
  const f16* pwk = pw + 144 * 512;
  const f16* pwv = pw + 264 * 512;
  const f16* pwo = pw + 384 * 512;

  // ---- S1: idx/mask (128 thr) + zero partials + LayerNorm (16 rows) -------
  if (tid < NJ) {
    const int j  = tid;
    const int q  = q0 + (j >> 3);
    const int id = idx_ws[((size_t)b * HW_ + q) * K_ + (j & 7)];
    s_idx[j] = id;
    const float ax = img_uv[id * 2], ay = img_uv[id * 2 + 1];
    const float bx2 = img_uv[q * 2], by2 = img_uv[q * 2 + 1];
    s_offx[j] = ax - bx2; s_offy[j] = ay - by2;
    const double dox = (double)ax - (double)bx2;
    const double doy = (double)ay - (double)by2;
    s_mask[j] = (dox * dox + doy * doy <= 0.010000000000000002) ? 1.f : 0.f;
  }
  if (tid < QT * NH_) s_qss[tid / NH_][tid % NH_] = 0.f;
  for (int o = tid; o < NJ * NH_; o += 256) {
    s_kss[o / NH_][o % NH_] = 0.f;
    s_ksc[o / NH_][o % NH_] = 0.f;
  }
  {
    const int r  = tid >> 4;                       // 0..15
    const int sl = tid & 15;
    const float* row = feat_2d + ((size_t)b * HW_ + q0 + r) * IMGD;
    float x[12]; float sum = 0.f, ssq = 0.f;
#pragma unroll
    for (int i = 0; i < 12; ++i) { x[i] = row[sl + 16 * i]; sum += x[i]; ssq += x[i] * x[i]; }
#pragma unroll
    for (int m = 8; m >= 1; m >>= 1) { sum += __shfl_xor(sum, m); ssq += __shfl_xor(ssq, m); }
    const float mu = sum * (1.f / 192.f);
    float var = ssq * (1.f / 192.f) - mu * mu;
    var = fmaxf(var, 0.f);
    const float rstd = rsqrtf(var + 1e-5f);
#pragma unroll
    for (int i = 0; i < 12; ++i) {
      const int c = sl + 16 * i;
      s_f16[r * AST + c] = (f16)((x[i] - mu) * rstd * ln_gamma[c]);
    }
  }
  __syncthreads();

  // ---- S2: X gather (2 thr/row), Q-MFMA (prefetch), pos-emb ---------------
  const int jX = tid >> 1, tsub = tid & 1;
  {
    const float4* f4 = reinterpret_cast<const float4*>(
        feat_3d + ((size_t)b * HW_ + s_idx[jX]) * PTD) + tsub * 16;
    f16* xr = &s_X[jX][tsub * 64];
#pragma unroll
    for (int half = 0; half < 2; ++half) {
      float4 xf[8];
#pragma unroll
      for (int i = 0; i < 8; ++i) xf[i] = f4[half * 8 + i];
#pragma unroll
      for (int i = 0; i < 8; ++i) {
        const int c = half * 32 + i * 4;
        xr[c + 0] = (f16)xf[i].x; xr[c + 1] = (f16)xf[i].y;
        xr[c + 2] = (f16)xf[i].z; xr[c + 3] = (f16)xf[i].w;
      }
    }
    if (tsub == 0) {
      const float ox = s_offx[jX], oy = s_offy[jX];
      f16* xp = &s_X[jX][PTD];
#pragma unroll
      for (int m = 0; m < 6; ++m) {
        const float fr = (float)(1 << m);
        float sx, cx, sy, cy;
        sincosf(ox * fr, &sx, &cx);
        sincosf(oy * fr, &sy, &cy);
        xp[m] = (f16)sx; xp[6 + m] = (f16)sy;
        xp[12 + m] = (f16)cx; xp[18 + m] = (f16)cy;
      }
      xp[24] = (f16)ox; xp[25] = (f16)oy;
#pragma unroll
      for (int m = 26; m < 32; ++m) xp[m] = (f16)0.f;   // pad k=154..159
    }
  }
  f32x4 qacc[6];
#pragma unroll
  for (int t = 0; t < 6; ++t) qacc[t] = (f32x4){0.f, 0.f, 0.f, 0.f};
  {
    const f16* ar = s_f16 + lm * AST + lg * 8;     // A row lm = query (all real)
    f16x8 acur = *(const f16x8*)(ar);
    f16x8 bcur[6], bnxt[6];
#pragma unroll
    for (int t = 0; t < 6; ++t)
      bcur[t] = *(const f16x8*)(pwq + ((((w * 6 + t) * 6 + 0) << 6) + l) * 8);
#pragma unroll
    for (int kt = 0; kt < KTQ; ++kt) {
      f16x8 anxt;
      if (kt < KTQ - 1) {
        anxt = *(const f16x8*)(ar + (kt + 1) * 32);
#pragma unroll
        for (int t = 0; t < 6; ++t)
          bnxt[t] = *(const f16x8*)(pwq + ((((w * 6 + t) * 6 + kt + 1) << 6) + l) * 8);
      }
#pragma unroll
      for (int t = 0; t < 6; ++t)
        qacc[t] = __builtin_amdgcn_mfma_f32_16x16x32_f16(acur, bcur[t], qacc[t], 0, 0, 0);
      if (kt < KTQ - 1) {
        acur = anxt;
#pragma unroll
        for (int t = 0; t < 6; ++t) bcur[t] = bnxt[t];
      }
    }
  }
  // barrier: Q-MFMA LDS reads (LN rows) complete before aliasing q-store
  __syncthreads();

  // ---- S2b: q fp32 store (16 rows, all lanes) + qss partial atomics -------
  {
    const int h0w = (w * 6) >> 2;                  // wave spans heads h0w, h0w+1
    float s2a[4], s2b[4];
#pragma unroll
    for (int reg = 0; reg < 4; ++reg) { s2a[reg] = 0.f; s2b[reg] = 0.f; }
#pragma unroll
    for (int t = 0; t < 6; ++t) {
      const int hi = ((w * 6 + t) >> 2) - h0w;     // 0 or 1, static per t
#pragma unroll
      for (int reg = 0; reg < 4; ++reg) {
        const float v = qacc[t][reg];
        s_regA[(lg * 4 + reg) * AST + (w * 6 + t) * 16 + lm] = v;
        if (hi == 0) s2a[reg] += v * v; else s2b[reg] += v * v;
      }
    }
#pragma unroll
    for (int reg = 0; reg < 4; ++reg) {
      atomicAdd(&s_qss[lg * 4 + reg][h0w], s2a[reg]);
      atomicAdd(&s_qss[lg * 4 + reg][h0w + 1], s2b[reg]);
    }
  }
  __syncthreads();

  // ---- S5: K-MFMA. Wave w -> nt = 4h+w; B-frags hoisted once (30 regs);
  //          8 m-tiles; q-scale folded; partial atomics. ---------------------
  {
    f16x8 bk[NH_][KTK];                            // 120 VGPRs, static indexed
#pragma unroll
    for (int h = 0; h < NH_; ++h) {
      const int nt = h * 4 + w;
#pragma unroll
      for (int kt = 0; kt < KTK; ++kt)
        bk[h][kt] = *(const f16x8*)(pwk + (((nt * KTK + kt) << 6) + l) * 8);
    }
#pragma unroll
    for (int mt = 0; mt < 8; ++mt) {
      const f16* xh = &s_X[16 * mt + lm][lg * 8];
      f16x8 af[KTK];
#pragma unroll
      for (int kt = 0; kt < KTK; ++kt) af[kt] = *(const f16x8*)(xh + kt * 32);
      const int rq = 2 * mt + (lg >> 1);
#pragma unroll
      for (int h = 0; h < NH_; ++h) {
        const int nt  = h * 4 + w;
        const int col = nt * 16 + lm;
        f32x4 c = (f32x4){0.f, 0.f, 0.f, 0.f};
#pragma unroll
        for (int kt = 0; kt < KTK; ++kt)
          c = __builtin_amdgcn_mfma_f32_16x16x32_f16(af[kt], bk[h][kt], c, 0, 0, 0);
        const float nnq = fmaxf(sqrtf(s_qss[rq][h]), 1e-12f);
        const float qg = s_regA[rq * AST + col] * (8.f / nnq)
                         * k_gamma[col] * q_gamma[col];
        float ss[4], sc[4];
#pragma unroll
        for (int reg = 0; reg < 4; ++reg) {
          const float v = c[reg];
          ss[reg] = v * v; sc[reg] = v * qg;
        }
#pragma unroll
        for (int m = 1; m < 16; m <<= 1) {
#pragma unroll
          for (int reg = 0; reg < 4; ++reg) {
            ss[reg] += __shfl_xor(ss[reg], m);
            sc[reg] += __shfl_xor(sc[reg], m);
          }
        }
        if (lm == 0) {
#pragma unroll
          for (int reg = 0; reg < 4; ++reg) {
            const int row = 16 * mt + 4 * lg + reg;
            atomicAdd(&s_kss[row][h], ss[reg]);
            atomicAdd(&s_ksc[row][h], sc[reg]);
          }
        }
      }
    }
  }
  __syncthreads();

  // ---- S6: finalize scores + masked softmax (96 thr) ----------------------
  if (tid < QT * NH_) {
    const int r = tid / NH_, h = tid % NH_;
    float s[K_]; float mx = -1e38f;
#pragma unroll
    for (int k = 0; k < K_; ++k) {
      const int row = r * K_ + k;
      const float nn = fmaxf(sqrtf(s_kss[row][h]), 1e-12f);
      float v = (8.f / nn) * s_ksc[row][h];
      if (s_mask[row] == 0.f) v = -1e30f;
      s[k] = v; mx = fmaxf(mx, v);
    }
    float sum = 0.f;
#pragma unroll
    for (int k = 0; k < K_; ++k) { const float pp = expf(s[k] - mx); s[k] = pp; sum += pp; }
    const float inv = 1.f / sum;
#pragma unroll
    for (int k = 0; k < K_; ++k) s_attn[r][h][k] = s[k] * inv;
  }
  __syncthreads();

  // ---- XB: xbar[96][160] (tile h = 16 queries) in regs, then write over X -
  f16x8 xbv[8];
#pragma unroll
  for (int rep = 0; rep < 8; ++rep) {
    const int task = tid + 256 * rep;
    if (task < 1920) {
      const int rhq = task / 20, cb = task - rhq * 20;
      const int h = rhq >> 4, q = rhq & 15;
      const float4 a0 = *(const float4*)&s_attn[q][h][0];
      const float4 a1 = *(const float4*)&s_attn[q][h][4];
      const float av[8] = {a0.x, a0.y, a0.z, a0.w, a1.x, a1.y, a1.z, a1.w};
      float acc[8];
#pragma unroll
      for (int e = 0; e < 8; ++e) acc[e] = 0.f;
#pragma unroll
      for (int k = 0; k < 8; ++k) {
        const f16x8 xv = *(const f16x8*)&s_X[q * 8 + k][cb * 8];
#pragma unroll
        for (int e = 0; e < 8; ++e) acc[e] += av[k] * (float)xv[e];
      }
      f16x8 rr;
#pragma unroll
      for (int e = 0; e < 8; ++e) rr[e] = (f16)acc[e];
      xbv[rep] = rr;
    }
  }
  __syncthreads();                                  // all X reads done
#pragma unroll
  for (int rep = 0; rep < 8; ++rep) {
    const int task = tid + 256 * rep;
    if (task < 1920) {
      const int rhq = task / 20, cb = task - rhq * 20;
      *(f16x8*)&s_X[rhq][cb * 8] = xbv[rep];        // row h*16+q
    }
  }
  __syncthreads();

  // ---- V: per-head V-MFMA (wave w -> nt = 4h+w) -> attn_out f16 [16][AST] -
  {
#pragma unroll
    for (int h = 0; h < NH_; ++h) {
      const int nt = h * 4 + w;
      const f16* xh = &s_X[h * 16 + lm][lg * 8];    // A row lm = query
      f16x8 af[KTK];
#pragma unroll
      for (int kt = 0; kt < KTK; ++kt) af[kt] = *(const f16x8*)(xh + kt * 32);
      f32x4 c = (f32x4){0.f, 0.f, 0.f, 0.f};
#pragma unroll
      for (int kt = 0; kt < KTK; ++kt) {
        const f16x8 bf = *(const f16x8*)(pwv + (((nt * KTK + kt) << 6) + l) * 8);
        c = __builtin_amdgcn_mfma_f32_16x16x32_f16(af[kt], bf, c, 0, 0, 0);
      }
#pragma unroll
      for (int reg = 0; reg < 4; ++reg) {
        const int q = lg * 4 + reg;                 // C row = query (all real)
        s_f16[q * AST + nt * 16 + lm] = (f16)c[reg];
      }
    }
  }
  __syncthreads();

  // ---- S8: out-projection fp16 MFMA, A all-real, 2-deep prefetch ----------
  {
    f32x4 oacc[6];
#pragma unroll
    for (int t = 0; t < 6; ++t) oacc[t] = (f32x4){0.f, 0.f, 0.f, 0.f};
    const f16* ar = s_f16 + lm * AST + lg * 8;
    f16x8 acur = *(const f16x8*)(ar);
    f16x8 bcur[6], bnxt[6];
#pragma unroll
    for (int t = 0; t < 6; ++t)
      bcur[t] = *(const f16x8*)(pwo + ((((w * 6 + t) * 12 + 0) << 6) + l) * 8);
#pragma unroll
    for (int kt = 0; kt < KTO; ++kt) {
      f16x8 anxt;
      if (kt < KTO - 1) {
        anxt = *(const f16x8*)(ar + (kt + 1) * 32);
#pragma unroll
        for (int t = 0; t < 6; ++t)
          bnxt[t] = *(const f16x8*)(pwo + ((((w * 6 + t) * 12 + kt + 1) << 6) + l) * 8);
      }
#pragma unroll
      for (int t = 0; t < 6; ++t)
        oacc[t] = __builtin_amdgcn_mfma_f32_16x16x32_f16(acur, bcur[t], oacc[t], 0, 0, 0);
      if (kt < KTO - 1) {
        acur = anxt;
#pragma unroll
        for (int t = 0; t < 6; ++t) bcur[t] = bnxt[t];
      }
    }
    {
      float* orow0 = out + ((size_t)b * HW_ + q0) * INNER;
#pragma unroll
      for (int reg = 0; reg < 4; ++reg) {
        const int m = lg * 4 + reg;                 // query row 0..15
#pragma unroll
        for (int t = 0; t < 6; ++t) {
          orow0[(size_t)m * INNER + (w * 6 + t) * 16 + lm] = oacc[t][reg];
        }
      }
    }
  }
}

// ---------------------------------------------------------------------------
extern "C" void kernel_launch(void* const* d_in, const int* in_sizes, int n_in,
                              void* d_out, int out_size, void* d_ws, size_t ws_size,
                              hipStream_t stream) {
  (void)in_sizes; (void)n_in; (void)out_size; (void)ws_size;
  const float* feat_2d = (const float*)d_in[0];
  const float* feat_3d = (const float*)d_in[1];
  const float* proj_uv = (const float*)d_in[2];
  const float* img_uv  = (const float*)d_in[3];
  const float* ln_g    = (const float*)d_in[4];
  const float* q_g     = (const float*)d_in[5];
  const float* k_g     = (const float*)d_in[6];
  const float* Wq      = (const float*)d_in[7];
  const float* Wkv     = (const float*)d_in[8];
  const float* Wout    = (const float*)d_in[9];
  float* out = (float*)d_out;

  // ws layout (16B-aligned chunks):
  //   idx    : int[B*HW*8]            = 614400 B  @ 0
  //   pw     : f16[672*512]           = 688128 B  @ 614400
  //   spts   : float2[B*HW]           = 153600 B  @ 1302528
  //   sidx   : u16[B*HW]              =  38400 B  @ 1456128
  //   cstart : u16[B*(NCELL+1)]       =  32776 B  @ 1494528
  int* idx_ws = (int*)d_ws;
  f16* pw = (f16*)((char*)d_ws + 614400);
  float2* spts = (float2*)((char*)d_ws + 1302528);
  unsigned short* sidx = (unsigned short*)((char*)d_ws + 1456128);
  unsigned short* cstart = (unsigned short*)((char*)d_ws + 1494528);

  pack_kernel<<<dim3(1344), 256, 0, stream>>>(Wq, Wkv, Wout, pw);
  build_kernel<<<dim3(B_), 1024, 0, stream>>>(proj_uv, spts, sidx, cstart);
  knn_kernel<<<dim3((HW_ + 255) / 256, B_), 256, 0, stream>>>(
      img_uv, spts, sidx, cstart, idx_ws);
  fused_kernel<<<dim3(HW_ / QT, B_), 256, 0, stream>>>(
      feat_2d, feat_3d, img_uv, ln_g, q_g, k_g, pw, idx_ws, out);
}

// Round 15
// 261.844 us; speedup vs baseline: 1.1164x; 1.1164x over previous
//
#include <hip/hip_runtime.h>
#include <math.h>

#define B_    4
#define HW_   4800
#define K_    8
#define IMGD  192
#define PTD   128
#define NH_   6
#define DH_   64
#define INNER 384
#define KVIN  154
#define QT    8
#define NJ    64
#define XBS   168    // fp16 X row stride (336B)
#define AST   392    // alias stride: f16 rows [16][AST], fp32 q rows [8][AST floats]
#define KTQ   6      // Q-proj k-steps (192)
#define KTK   5      // K/V k-steps (154 -> 160, zero-padded both sides)
#define KTO   12     // out-proj k-steps (384)

#define GC    64     // kNN bucket grid cells per dim
#define NCELL (GC * GC)
#define CS    (1.0f / 64.0f)
#define NBX   ((HW_ + 255) / 256)        // 19 knn blocks per batch

typedef _Float16 f16;
typedef __attribute__((ext_vector_type(8))) _Float16 f16x8;
typedef __attribute__((ext_vector_type(4))) float f32x4;

// ---------------------------------------------------------------------------
// Kernel B: per-batch counting sort of proj_uv into a 64x64 cell grid.
// ---------------------------------------------------------------------------
__global__ __launch_bounds__(1024) void build_kernel(
    const float* __restrict__ proj_uv,
    float2* __restrict__ spts,
    unsigned short* __restrict__ sidx,
    unsigned short* __restrict__ cstart)
{
  __shared__ unsigned cnt[NCELL];
  __shared__ unsigned start[NCELL];
  __shared__ unsigned wsum[16];

  const int b   = blockIdx.x;
  const int tid = threadIdx.x;
  const int lane = tid & 63, wid = tid >> 6;
  const float2* pv = reinterpret_cast<const float2*>(proj_uv + (size_t)b * HW_ * 2);

  for (int c = tid; c < NCELL; c += 1024) cnt[c] = 0u;
  __syncthreads();

  for (int i = tid; i < HW_; i += 1024) {
    const float2 p = pv[i];
    const int cx = min(GC - 1, max(0, (int)(p.x * GC)));
    const int cy = min(GC - 1, max(0, (int)(p.y * GC)));
    atomicAdd(&cnt[cy * GC + cx], 1u);
  }
  __syncthreads();

  const int c0 = tid * 4;
  const unsigned v0 = cnt[c0], v1 = cnt[c0 + 1], v2 = cnt[c0 + 2], v3 = cnt[c0 + 3];
  const unsigned mysum = v0 + v1 + v2 + v3;
  unsigned inc = mysum;
#pragma unroll
  for (int off = 1; off < 64; off <<= 1) {
    const unsigned u = (unsigned)__shfl_up((int)inc, off);
    if (lane >= off) inc += u;
  }
  if (lane == 63) wsum[wid] = inc;
  __syncthreads();
  if (tid == 0) {
    unsigned s = 0;
#pragma unroll
    for (int wv = 0; wv < 16; ++wv) { const unsigned t = wsum[wv]; wsum[wv] = s; s += t; }
  }
  __syncthreads();
  unsigned base = wsum[wid] + inc - mysum;
  start[c0] = base;
  start[c0 + 1] = base + v0;
  start[c0 + 2] = base + v0 + v1;
  start[c0 + 3] = base + v0 + v1 + v2;
  unsigned short* cs = cstart + (size_t)b * (NCELL + 1);
  cs[c0]     = (unsigned short)start[c0];
  cs[c0 + 1] = (unsigned short)start[c0 + 1];
  cs[c0 + 2] = (unsigned short)start[c0 + 2];
  cs[c0 + 3] = (unsigned short)start[c0 + 3];
  if (tid == 0) cs[NCELL] = (unsigned short)HW_;
  __syncthreads();

  for (int i = tid; i < HW_; i += 1024) {
    const float2 p = pv[i];
    const int cx = min(GC - 1, max(0, (int)(p.x * GC)));
    const int cy = min(GC - 1, max(0, (int)(p.y * GC)));
    const unsigned slot = atomicAdd(&start[cy * GC + cx], 1u);
    spts[(size_t)b * HW_ + slot] = p;
    sidx[(size_t)b * HW_ + slot] = (unsigned short)i;
  }
}

// ---------------------------------------------------------------------------
// Kernel 1: kNN via ring scan over the cell grid (r11-fixed, r12/13-passed),
// with the weight-pack folded in as a grid-stride prologue (saves a dispatch;
// pattern validated in r9). Pack layout: frag element (l,j):
// k = kt*32+(l>>4)*8+j, n = nt*16+(l&15);
// [pwq f=0..143 | pwk 144..263 | pwv 264..383 | pwo 384..671], 512 elems/frag
// ---------------------------------------------------------------------------
#define SCAN_CELL(cyv, cxv)                                                   \
  {                                                                           \
    const int c = (cyv) * GC + (cxv);                                         \
    const int s0 = s_cs[c], s1 = s_cs[c + 1];                                 \
    for (int s = s0; s < s1; ++s) {                                           \
      const float2 p = s_p[s];                                                \
      const int n = (int)s_i[s];                                              \
      const float sqp = p.x * p.x + p.y * p.y;       /* f32 no fma */         \
      const float dot = fmaf(qy, p.y, qx * p.x);     /* BLAS K=2 fma */       \
      const float d   = (sqq + sqp) - 2.0f * dot;                             \
      const bool enter = (d < dist[K_ - 1]) ||                                \
                         (d == dist[K_ - 1] && n < ind[K_ - 1]);              \
      if (enter) {                                                            \
        bool placed = false;                                                  \
        _Pragma("unroll")                                                     \
        for (int t = K_ - 1; t >= 1; --t) {                                   \
          if (!placed) {                                                      \
            const bool lt = (d < dist[t - 1]) ||                              \
                            (d == dist[t - 1] && n < ind[t - 1]);             \
            if (lt) { dist[t] = dist[t - 1]; ind[t] = ind[t - 1]; }           \
            else    { dist[t] = d; ind[t] = n; placed = true; }               \
          }                                                                   \
        }                                                                     \
        if (!placed) { dist[0] = d; ind[0] = n; }                             \
      }                                                                       \
    }                                                                         \
  }

__global__ __launch_bounds__(256) void knn_kernel(
    const float* __restrict__ img_uv,
    const float2* __restrict__ spts,
    const unsigned short* __restrict__ sidx,
    const unsigned short* __restrict__ cstart,
    const float* __restrict__ Wq, const float* __restrict__ Wkv,
    const float* __restrict__ Wout, f16* __restrict__ pw,
    int* __restrict__ idx_out)
{
#pragma clang fp contract(off)
  __shared__ float2 s_p[HW_];
  __shared__ unsigned short s_i[HW_];
  __shared__ unsigned short s_cs[NCELL + 1];

  const int tid = threadIdx.x;
  const int b   = blockIdx.y;
  const int q   = blockIdx.x * 256 + tid;

  // ---- folded weight pack (grid-stride over 344064 elems, ~18 iters/thr) --
  {
    const int blin = b * NBX + blockIdx.x;
    for (int e = blin * 256 + tid; e < 672 * 512; e += NBX * B_ * 256) {
      const int f = e >> 9, r = e & 511, l = r >> 3, j = r & 7;
      const int lm = l & 15, kin = (l >> 4) * 8 + j;
      float v;
      if (f < 144) {                                // Wq [192][384]
        const int nt = f / 6, kt = f % 6;
        v = Wq[(size_t)(kt * 32 + kin) * INNER + nt * 16 + lm];
      } else if (f < 264) {                         // Wk = Wkv[:, :384]
        const int g = f - 144, nt = g / 5, kt = g % 5, k = kt * 32 + kin;
        v = (k < KVIN) ? Wkv[(size_t)k * (2 * INNER) + nt * 16 + lm] : 0.f;
      } else if (f < 384) {                         // Wv = Wkv[:, 384:]
        const int g = f - 264, nt = g / 5, kt = g % 5, k = kt * 32 + kin;
        v = (k < KVIN) ? Wkv[(size_t)k * (2 * INNER) + INNER + nt * 16 + lm] : 0.f;
      } else {                                      // Wout [384][384]
        const int g = f - 384, nt = g / 12, kt = g % 12;
        v = Wout[(size_t)(kt * 32 + kin) * INNER + nt * 16 + lm];
      }
      pw[e] = (f16)v;
    }
  }

  {
    const float2* gp = spts + (size_t)b * HW_;
    const unsigned short* gi = sidx + (size_t)b * HW_;
    const unsigned short* gc = cstart + (size_t)b * (NCELL + 1);
    for (int i = tid; i < HW_; i += 256) { s_p[i] = gp[i]; s_i[i] = gi[i]; }
    for (int i = tid; i < NCELL + 1; i += 256) s_cs[i] = gc[i];
  }
  __syncthreads();
  if (q >= HW_) return;

  const float qx = img_uv[q * 2 + 0];
  const float qy = img_uv[q * 2 + 1];
  const float sqq = qx * qx + qy * qy;             // square-then-sum, no fma

  const int cellx = min(GC - 1, max(0, (int)(qx * GC)));
  const int celly = min(GC - 1, max(0, (int)(qy * GC)));

  float dist[K_];
  int   ind[K_];
#pragma unroll
  for (int s = 0; s < K_; ++s) { dist[s] = 3.4e38f; ind[s] = 0x7fffffff; }

  for (int r = 0; r < GC; ++r) {
    if (r >= 2 && dist[K_ - 1] < 1e38f) {
      const float rb = (float)(r - 1) * CS;        // min true dist of ring r
      if (rb * rb > dist[K_ - 1] + 1e-4f) break;   // margin >> f32 formula err
    }
    const int ylo = max(0, celly - r), yhi = min(GC - 1, celly + r);
    for (int cy = ylo; cy <= yhi; ++cy) {
      const bool edge = (cy == celly - r) || (cy == celly + r);
      if (edge) {
        const int xlo = max(0, cellx - r), xhi = min(GC - 1, cellx + r);
        for (int cx = xlo; cx <= xhi; ++cx) SCAN_CELL(cy, cx);
      } else {
        if (cellx - r >= 0)      SCAN_CELL(cy, cellx - r);
        if (cellx + r <= GC - 1) SCAN_CELL(cy, cellx + r);
      }
    }
  }

  int* dst = idx_out + ((size_t)b * HW_ + q) * K_;
#pragma unroll
  for (int s = 0; s < K_; ++s) dst[s] = ind[s];
}

// ---------------------------------------------------------------------------
// Kernel 2: fused fp16-MFMA pipeline (r13 configuration — best measured:
// 201 µs steady-state, passed). __launch_bounds__(256,3), A-frags hoisted,
// B-frag prefetch, barrier between Q-MFMA LDS reads and aliasing q-store.
// ---------------------------------------------------------------------------
__global__ __launch_bounds__(256, 3) void fused_kernel(
    const float* __restrict__ feat_2d,
    const float* __restrict__ feat_3d,
    const float* __restrict__ img_uv,
    const float* __restrict__ ln_gamma,
    const float* __restrict__ q_gamma,
    const float* __restrict__ k_gamma,
    const f16*   __restrict__ pw,
    const int*   __restrict__ idx_ws,
    float* __restrict__ out)
{
  __shared__ alignas(16) f16   s_X[NJ][XBS];       // X rows; later xbar[48]
  __shared__ alignas(16) float s_regA[QT * AST];   // q fp32 | alias f16[16][AST]
  __shared__ alignas(16) float s_attn[QT][NH_][K_];
  __shared__ alignas(16) float s_kss[NJ][NH_];
  __shared__ alignas(16) float s_ksc[NJ][NH_];
  __shared__ float s_qss[QT][NH_];
  __shared__ float s_mask[NJ];
  __shared__ int   s_idx[NJ];
  __shared__ float s_offx[NJ];
  __shared__ float s_offy[NJ];

  f16* s_f16 = reinterpret_cast<f16*>(s_regA);     // [16][AST]

  const int tid = threadIdx.x;
  const int b   = blockIdx.y;
  const int bx  = (blockIdx.x & 7) * 75 + (blockIdx.x >> 3);  // XCD swizzle
  const int q0  = bx * QT;
  const int l   = tid & 63;
  const int w   = tid >> 6;                        // 0..3
  const int lm  = l & 15;
  const int lg  = l >> 4;

  const f16* pwq = pw;
  const f16* pwk = pw + 144 * 512;
  const f16* pwv = pw + 264 * 512;
  const f16* pwo = pw + 384 * 512;

  // ---- S1: idx/mask + zero (alias rows 8..15, qss, kss, ksc) + LayerNorm --
  if (tid < NJ) {
    const int j  = tid;
    const int q  = q0 + (j >> 3);
    const int id = idx_ws[((size_t)b * HW_ + q) * K_ + (j & 7)];
    s_idx[j] = id;
    const float ax = img_uv[id * 2], ay = img_uv[id * 2 + 1];
    const float bx2 = img_uv[q * 2], by2 = img_uv[q * 2 + 1];
    s_offx[j] = ax - bx2; s_offy[j] = ay - by2;
    const double dox = (double)ax - (double)bx2;
    const double doy = (double)ay - (double)by2;
    s_mask[j] = (dox * dox + doy * doy <= 0.010000000000000002) ? 1.f : 0.f;
  }
  {
    unsigned* z = (unsigned*)(s_f16 + 8 * AST);
    for (int o = tid; o < 4 * AST; o += 256) z[o] = 0u;
  }
  if (tid < QT * NH_) s_qss[tid / NH_][tid % NH_] = 0.f;
  for (int o = tid; o < NJ * NH_; o += 256) {
    s_kss[o / NH_][o % NH_] = 0.f;
    s_ksc[o / NH_][o % NH_] = 0.f;
  }
  {
    const int r  = ((tid >> 6) << 1) | ((tid >> 5) & 1);
    const int sl = tid & 31;
    const float* row = feat_2d + ((size_t)b * HW_ + q0 + r) * IMGD;
    float x[6]; float sum = 0.f, ssq = 0.f;
#pragma unroll
    for (int i = 0; i < 6; ++i) { x[i] = row[sl + 32 * i]; sum += x[i]; ssq += x[i] * x[i]; }
#pragma unroll
    for (int m = 16; m >= 1; m >>= 1) { sum += __shfl_xor(sum, m); ssq += __shfl_xor(ssq, m); }
    const float mu = sum * (1.f / 192.f);
    float var = ssq * (1.f / 192.f) - mu * mu;
    var = fmaxf(var, 0.f);
    const float rstd = rsqrtf(var + 1e-5f);
#pragma unroll
    for (int i = 0; i < 6; ++i) {
      const int c = sl + 32 * i;
      s_f16[r * AST + c] = (f16)((x[i] - mu) * rstd * ln_gamma[c]);
    }
  }
  __syncthreads();

  // ---- S2: X loads (early), Q-MFMA (B-prefetch), X write + pos-emb --------
  const int jX = tid >> 2, tsub = tid & 3;
  float4 xf[8];
  {
    const float4* f4 = reinterpret_cast<const float4*>(
        feat_3d + ((size_t)b * HW_ + s_idx[jX]) * PTD) + tsub * 8;
#pragma unroll
    for (int i = 0; i < 8; ++i) xf[i] = f4[i];
  }
  f32x4 qacc[6];
#pragma unroll
  for (int t = 0; t < 6; ++t) qacc[t] = (f32x4){0.f, 0.f, 0.f, 0.f};
  {
    const f16* ar = s_f16 + lm * AST + lg * 8;
    f16x8 acur = *(const f16x8*)(ar);
    f16x8 bcur[6], bnxt[6];
#pragma unroll
    for (int t = 0; t < 6; ++t)
      bcur[t] = *(const f16x8*)(pwq + ((((w * 6 + t) * 6 + 0) << 6) + l) * 8);
#pragma unroll
    for (int kt = 0; kt < KTQ; ++kt) {
      f16x8 anxt;
      if (kt < KTQ - 1) {
        anxt = *(const f16x8*)(ar + (kt + 1) * 32);
#pragma unroll
        for (int t = 0; t < 6; ++t)
          bnxt[t] = *(const f16x8*)(pwq + ((((w * 6 + t) * 6 + kt + 1) << 6) + l) * 8);
      }
#pragma unroll
      for (int t = 0; t < 6; ++t)
        qacc[t] = __builtin_amdgcn_mfma_f32_16x16x32_f16(acur, bcur[t], qacc[t], 0, 0, 0);
      if (kt < KTQ - 1) {
        acur = anxt;
#pragma unroll
        for (int t = 0; t < 6; ++t) bcur[t] = bnxt[t];
      }
    }
  }
  {
    f16* xr = &s_X[jX][tsub * 32];
#pragma unroll
    for (int i = 0; i < 8; ++i) {
      xr[i * 4 + 0] = (f16)xf[i].x; xr[i * 4 + 1] = (f16)xf[i].y;
      xr[i * 4 + 2] = (f16)xf[i].z; xr[i * 4 + 3] = (f16)xf[i].w;
    }
    if (tsub == 0) {
      const float ox = s_offx[jX], oy = s_offy[jX];
      f16* xp = &s_X[jX][PTD];
#pragma unroll
      for (int m = 0; m < 6; ++m) {
        const float fr = (float)(1 << m);
        float sx, cx, sy, cy;
        sincosf(ox * fr, &sx, &cx);
        sincosf(oy * fr, &sy, &cy);
        xp[m] = (f16)sx; xp[6 + m] = (f16)sy;
        xp[12 + m] = (f16)cx; xp[18 + m] = (f16)cy;
      }
      xp[24] = (f16)ox; xp[25] = (f16)oy;
#pragma unroll
      for (int m = 26; m < 32; ++m) xp[m] = (f16)0.f;   // pad k=154..159
    }
  }
  // barrier: all waves' Q-MFMA LDS reads (LN rows) complete BEFORE the
  // aliasing fp32 q-store below
  __syncthreads();

  // ---- S2b: q store + qss partial atomics ---------------------------------
  if (lg < 2) {
    const int h0w = (w * 6) >> 2;
    float s2a[4], s2b[4];
#pragma unroll
    for (int reg = 0; reg < 4; ++reg) { s2a[reg] = 0.f; s2b[reg] = 0.f; }
#pragma unroll
    for (int t = 0; t < 6; ++t) {
      const int hi = ((w * 6 + t) >> 2) - h0w;     // 0 or 1 (static per t)
#pragma unroll
      for (int reg = 0; reg < 4; ++reg) {
        const float v = qacc[t][reg];
        s_regA[(lg * 4 + reg) * AST + (w * 6 + t) * 16 + lm] = v;
        if (hi == 0) s2a[reg] += v * v; else s2b[reg] += v * v;
      }
    }
#pragma unroll
    for (int reg = 0; reg < 4; ++reg) {
      atomicAdd(&s_qss[lg * 4 + reg][h0w], s2a[reg]);
      atomicAdd(&s_qss[lg * 4 + reg][h0w + 1], s2b[reg]);
    }
  }
  __syncthreads();

  // ---- S5: K-MFMA, A-frags hoisted (20 regs), B double-buffered over h ----
  {
    f16x8 af[4][KTK];                              // 80 VGPRs, static indexed
#pragma unroll
    for (int mt = 0; mt < 4; ++mt) {
      const f16* xh = &s_X[16 * mt + lm][lg * 8];
#pragma unroll
      for (int kt = 0; kt < KTK; ++kt) af[mt][kt] = *(const f16x8*)(xh + kt * 32);
    }
    f16x8 bcur[KTK], bnxt[KTK];
#pragma unroll
    for (int kt = 0; kt < KTK; ++kt)
      bcur[kt] = *(const f16x8*)(pwk + (((w * KTK + kt) << 6) + l) * 8);  // h=0
#pragma unroll
    for (int h = 0; h < NH_; ++h) {
      if (h < NH_ - 1) {
        const int ntn = (h + 1) * 4 + w;
#pragma unroll
        for (int kt = 0; kt < KTK; ++kt)
          bnxt[kt] = *(const f16x8*)(pwk + (((ntn * KTK + kt) << 6) + l) * 8);
      }
      const int nt  = h * 4 + w;
      const int col = nt * 16 + lm;
      const float gg = k_gamma[col] * q_gamma[col];
      f32x4 c[4];
#pragma unroll
      for (int mt = 0; mt < 4; ++mt) c[mt] = (f32x4){0.f, 0.f, 0.f, 0.f};
#pragma unroll
      for (int kt = 0; kt < KTK; ++kt)
#pragma unroll
        for (int mt = 0; mt < 4; ++mt)
          c[mt] = __builtin_amdgcn_mfma_f32_16x16x32_f16(af[mt][kt], bcur[kt], c[mt], 0, 0, 0);
#pragma unroll
      for (int mt = 0; mt < 4; ++mt) {
        const int rq = 2 * mt + (lg >> 1);
        const float nnq = fmaxf(sqrtf(s_qss[rq][h]), 1e-12f);
        const float qg = s_regA[rq * AST + col] * (8.f / nnq) * gg;
        float ss[4], sc[4];
#pragma unroll
        for (int reg = 0; reg < 4; ++reg) {
          const float v = c[mt][reg];
          ss[reg] = v * v; sc[reg] = v * qg;
        }
#pragma unroll
        for (int m = 1; m < 16; m <<= 1) {
#pragma unroll
          for (int reg = 0; reg < 4; ++reg) {
            ss[reg] += __shfl_xor(ss[reg], m);
            sc[reg] += __shfl_xor(sc[reg], m);
          }
        }
        if (lm == 0) {
#pragma unroll
          for (int reg = 0; reg < 4; ++reg) {
            const int row = 16 * mt + 4 * lg + reg;
            atomicAdd(&s_kss[row][h], ss[reg]);
            atomicAdd(&s_ksc[row][h], sc[reg]);
          }
        }
      }
      if (h < NH_ - 1) {
#pragma unroll
        for (int kt = 0; kt < KTK; ++kt) bcur[kt] = bnxt[kt];
      }
    }
  }
  __syncthreads();

  // ---- S6: finalize scores + masked softmax (48 thr, fused) ---------------
  if (tid < QT * NH_) {
    const int r = tid / NH_, h = tid % NH_;
    float s[K_]; float mx = -1e38f;
#pragma unroll
    for (int k = 0; k < K_; ++k) {
      const int row = r * K_ + k;
      const float nn = fmaxf(sqrtf(s_kss[row][h]), 1e-12f);
      float v = (8.f / nn) * s_ksc[row][h];
      if (s_mask[row] == 0.f) v = -1e30f;
      s[k] = v; mx = fmaxf(mx, v);
    }
    float sum = 0.f;
#pragma unroll
    for (int k = 0; k < K_; ++k) { const float pp = expf(s[k] - mx); s[k] = pp; sum += pp; }
    const float inv = 1.f / sum;
#pragma unroll
    for (int k = 0; k < K_; ++k) s_attn[r][h][k] = s[k] * inv;
  }
  __syncthreads();

  // ---- XB: build xbar[48][160] in registers; zero f16 rows 8..15 ----------
  {
    unsigned* z = (unsigned*)(s_f16 + 8 * AST);
    for (int o = tid; o < 4 * AST; o += 256) z[o] = 0u;
  }
  f16x8 xbv[4];
#pragma unroll
  for (int rep = 0; rep < 4; ++rep) {
    const int task = tid + 256 * rep;
    if (task < 960) {
      const int p = task / 320, rem = task - p * 320;
      const int r16 = rem / 20, cb = rem - r16 * 20;
      const int q = r16 & 7, hh = 2 * p + (r16 >> 3);
      const float4 a0 = *(const float4*)&s_attn[q][hh][0];
      const float4 a1 = *(const float4*)&s_attn[q][hh][4];
      const float av[8] = {a0.x, a0.y, a0.z, a0.w, a1.x, a1.y, a1.z, a1.w};
      float acc[8];
#pragma unroll
      for (int e = 0; e < 8; ++e) acc[e] = 0.f;
#pragma unroll
      for (int k = 0; k < 8; ++k) {
        const f16x8 xv = *(const f16x8*)&s_X[q * 8 + k][cb * 8];
#pragma unroll
        for (int e = 0; e < 8; ++e) acc[e] += av[k] * (float)xv[e];
      }
      f16x8 rr;
#pragma unroll
      for (int e = 0; e < 8; ++e) rr[e] = (f16)acc[e];
      xbv[rep] = rr;
    }
  }
  __syncthreads();                                  // all X reads done
#pragma unroll
  for (int rep = 0; rep < 4; ++rep) {
    const int task = tid + 256 * rep;
    if (task < 960) {
      const int p = task / 320, rem = task - p * 320;
      const int r16 = rem / 20, cb = rem - r16 * 20;
      *(f16x8*)&s_X[p * 16 + r16][cb * 8] = xbv[rep];
    }
  }
  __syncthreads();

  // ---- V: pair-packed V-MFMA -> attn_out fp16 rows 0..7 of s_f16 ----------
  {
#pragma unroll
    for (int p = 0; p < 3; ++p) {
      f16x8 af[KTK];
#pragma unroll
      for (int kt = 0; kt < KTK; ++kt)
        af[kt] = *(const f16x8*)&s_X[p * 16 + lm][lg * 8 + kt * 32];
#pragma unroll
      for (int ii = 0; ii < 2; ++ii) {
        const int nt = w + 4 * (2 * p + ii);
        const int h  = nt >> 2;
        f32x4 c = (f32x4){0.f, 0.f, 0.f, 0.f};
#pragma unroll
        for (int kt = 0; kt < KTK; ++kt) {
          const f16x8 bf = *(const f16x8*)(pwv + (((nt * KTK + kt) << 6) + l) * 8);
          c = __builtin_amdgcn_mfma_f32_16x16x32_f16(af[kt], bf, c, 0, 0, 0);
        }
        if ((lg >> 1) == (h & 1)) {                 // this lane's rows match head
#pragma unroll
          for (int reg = 0; reg < 4; ++reg) {
            const int q = (lg * 4 + reg) & 7;
            s_f16[q * AST + nt * 16 + lm] = (f16)c[reg];
          }
        }
      }
    }
  }
  __syncthreads();

  // ---- S8: out-projection fp16 MFMA, 2-deep A/B prefetch ------------------
  {
    f32x4 oacc[6];
#pragma unroll
    for (int t = 0; t < 6; ++t) oacc[t] = (f32x4){0.f, 0.f, 0.f, 0.f};
    const f16* ar = s_f16 + lm * AST + lg * 8;
    f16x8 acur = *(const f16x8*)(ar);
    f16x8 bcur[6], bnxt[6];
#pragma unroll
    for (int t = 0; t < 6; ++t)
      bcur[t] = *(const f16x8*)(pwo + ((((w * 6 + t) * 12 + 0) << 6) + l) * 8);
#pragma unroll
    for (int kt = 0; kt < KTO; ++kt) {
      f16x8 anxt;
      if (kt < KTO - 1) {
        anxt = *(const f16x8*)(ar + (kt + 1) * 32);
#pragma unroll
        for (int t = 0; t < 6; ++t)
          bnxt[t] = *(const f16x8*)(pwo + ((((w * 6 + t) * 12 + kt + 1) << 6) + l) * 8);
      }
#pragma unroll
      for (int t = 0; t < 6; ++t)
        oacc[t] = __builtin_amdgcn_mfma_f32_16x16x32_f16(acur, bcur[t], oacc[t], 0, 0, 0);
      if (kt < KTO - 1) {
        acur = anxt;
#pragma unroll
        for (int t = 0; t < 6; ++t) bcur[t] = bnxt[t];
      }
    }
    if (lg < 2) {
      float* orow0 = out + ((size_t)b * HW_ + q0) * INNER;
#pragma unroll
      for (int reg = 0; reg < 4; ++reg) {
        const int m = lg * 4 + reg;
#pragma unroll
        for (int t = 0; t < 6; ++t) {
          orow0[(size_t)m * INNER + (w * 6 + t) * 16 + lm] = oacc[t][reg];
        }
      }
    }
  }
}

// ---------------------------------------------------------------------------
extern "C" void kernel_launch(void* const* d_in, const int* in_sizes, int n_in,
                              void* d_out, int out_size, void* d_ws, size_t ws_size,
                              hipStream_t stream) {
  (void)in_sizes; (void)n_in; (void)out_size; (void)ws_size;
  const float* feat_2d = (const float*)d_in[0];
  const float* feat_3d = (const float*)d_in[1];
  const float* proj_uv = (const float*)d_in[2];
  const float* img_uv  = (const float*)d_in[3];
  const float* ln_g    = (const float*)d_in[4];
  const float* q_g     = (const float*)d_in[5];
  const float* k_g     = (const float*)d_in[6];
  const float* Wq      = (const float*)d_in[7];
  const float* Wkv     = (const float*)d_in[8];
  const float* Wout    = (const float*)d_in[9];
  float* out = (float*)d_out;

  // ws layout (16B-aligned chunks):
  //   idx    : int[B*HW*8]            = 614400 B  @ 0
  //   pw     : f16[672*512]           = 688128 B  @ 614400
  //   spts   : float2[B*HW]           = 153600 B  @ 1302528
  //   sidx   : u16[B*HW]              =  38400 B  @ 1456128
  //   cstart : u16[B*(NCELL+1)]       =  32776 B  @ 1494528
  int* idx_ws = (int*)d_ws;
  f16* pw = (f16*)((char*)d_ws + 614400);
  float2* spts = (float2*)((char*)d_ws + 1302528);
  unsigned short* sidx = (unsigned short*)((char*)d_ws + 1456128);
  unsigned short* cstart = (unsigned short*)((char*)d_ws + 1494528);

  build_kernel<<<dim3(B_), 1024, 0, stream>>>(proj_uv, spts, sidx, cstart);
  knn_kernel<<<dim3(NBX, B_), 256, 0, stream>>>(
      img_uv, spts, sidx, cstart, Wq, Wkv, Wout, pw, idx_ws);
  fused_kernel<<<dim3(HW_ / QT, B_), 256, 0, stream>>>(
      feat_2d, feat_3d, img_uv, ln_g, q_g, k_g, pw, idx_ws, out);
}